// Round 2
// baseline (657.023 us; speedup 1.0000x reference)
//
#include <hip/hip_runtime.h>
#include <stdint.h>

// ---------------------------------------------------------------------------
// Fastformer, MI355X gfx950.  Round 6 = round 5 resubmit (round-5 bench died
// with a container-level infra error; kernel audited clean for OOB/hang).
// Algebraic collapse: every use of Q/K is linear in X =>
//   q_scores = X @ (Wq@Wqa)                      (Wqeff, 768x12, static)
//   q_ctx    = ((sum_s e_q X) @ Wq) / sum(e_q)   (per-h weighted X sums)
//   k_scores = X @ (Wk diag(qctx) Wka)           (Wkeff_b, 768x12, per batch)
//   k_ctx    = qctx * ((sum_s e_k X) @ Wk)/sum
//   out      = X @ (Wq blockdiag_h(I + diag(k_ctx_b) Wo))   (one GEMM!)
// Qb/Kb (100 MB write + ~200 MB re-read) and the old out_kernel vanish.
// Launches: memset(1KB), prep, xsum(q), ctx(q), wkeff, xsum(k), ctx(k),
//           buildbt, gemm_out.
// ---------------------------------------------------------------------------

#define AS1 __attribute__((address_space(1)))
#define AS3 __attribute__((address_space(3)))

typedef __attribute__((ext_vector_type(8))) __bf16   bf16x8;
typedef __attribute__((ext_vector_type(8))) uint16_t u16x8;
typedef __attribute__((ext_vector_type(4))) float    f32x4;

__device__ __forceinline__ float bf2f(uint16_t v) {
  union { uint32_t u; float f; } x; x.u = ((uint32_t)v) << 16; return x.f;
}
__device__ __forceinline__ uint16_t f2bf(float f) {
  uint32_t u = __float_as_uint(f);
  uint32_t r = (u + 0x7fffu + ((u >> 16) & 1u)) >> 16;
  return (uint16_t)r;
}
__device__ __forceinline__ bf16x8 cvt8(const float4 lo, const float4 hi) {
  u16x8 r;
  r[0] = f2bf(lo.x); r[1] = f2bf(lo.y); r[2] = f2bf(lo.z); r[3] = f2bf(lo.w);
  r[4] = f2bf(hi.x); r[5] = f2bf(hi.y); r[6] = f2bf(hi.z); r[7] = f2bf(hi.w);
  union { u16x8 u; bf16x8 b; } c; c.u = r; return c.b;
}
// async global->LDS, 16 B/lane; LDS dest must be lane-contiguous (tid*16B).
__device__ __forceinline__ void gload16(const void* g, void* l) {
  __builtin_amdgcn_global_load_lds((AS1 void*)(void*)g, (AS3 void*)l, 16, 0, 0);
}

// ---------------------------------------------------------------------------
// prep: job0 cvt X->Xb (12288 blocks) | job1 WT=bf16(Wq^T|Wk^T) (4608)
//       | job2 WqeffT[hp][k] = bf16((Wq@Wqa)[k][hp]) (48 blocks)
__global__ __launch_bounds__(256) void prep_kernel(
    const float* __restrict__ X, const float* __restrict__ Wq,
    const float* __restrict__ Wk, const float* __restrict__ Wqa,
    uint16_t* __restrict__ Xb, uint16_t* __restrict__ WT,
    uint16_t* __restrict__ WqeffT) {
  const int bid = blockIdx.x, tid = threadIdx.x;
  if (bid < 12288) {
    size_t i = ((size_t)bid * 256 + tid) * 8;
    const float* p = X + i;
    *(bf16x8*)(Xb + i) = cvt8(*(const float4*)p, *(const float4*)(p + 4));
  } else if (bid < 16896) {
    int i = (bid - 12288) * 256 + tid;          // 0..1179647
    int j = (i < 589824) ? i : i - 589824;
    const float* src = (i < 589824) ? Wq : Wk;
    int n = j / 768, k = j - n * 768;
    WT[i] = f2bf(src[k * 768 + n]);
  } else {
    int i = (bid - 16896) * 256 + tid;          // 0..12287
    int hp = i & 15, kin = i >> 4;
    if (hp < 12) {
      float acc = 0.f;
#pragma unroll 4
      for (int c = 0; c < 768; c++) acc += Wq[kin * 768 + c] * Wqa[c * 12 + hp];
      WqeffT[hp * 768 + kin] = f2bf(acc);
    } else {
      WqeffT[hp * 768 + kin] = 0;
    }
  }
}

// ---------------------------------------------------------------------------
// xsum: per 128-row block.  Phase 1: scores = Xb @ BT^T (MFMA, N=16 rows of
// BT = per-h projection), e = exp(s/8)*mask into LDS; per-h sum(e) atomics.
// Phase 2: per-h weighted X sums -> per-block partial slab (plain stores).
__global__ __launch_bounds__(256) void xsum_kernel(
    const uint16_t* __restrict__ Xb, const uint16_t* __restrict__ BT,
    const float* __restrict__ mask, int bStride,
    float* __restrict__ part, float* __restrict__ sume) {
  __shared__ __align__(16) uint16_t Bs[16 * 768];  // 24 KB
  __shared__ __align__(16) uint16_t As[128 * 32];  // 8 KB
  __shared__ __align__(16) float eS[128 * 16];     // 8 KB
  __shared__ float ps[192];
  const int tid = threadIdx.x;
  const int bid = blockIdx.x;            // 256 blocks; 32 per batch
  const int m0  = bid * 128;
  const int b   = m0 >> 12;
  const uint16_t* BTb = BT + (size_t)b * bStride;
#pragma unroll
  for (int p = 0; p < 6; p++)
    gload16(BTb + (size_t)(p * 256 + tid) * 8, Bs + (p * 256 + tid) * 8);
  const int wave = tid >> 6, lane = tid & 63, lr = lane & 15, lk = lane >> 4;
  const f32x4 zero = {0.f, 0.f, 0.f, 0.f};
  f32x4 acc0 = zero, acc1 = zero;
  const int lrow = tid >> 2, lseg = (tid & 3) * 8;
  for (int k0 = 0; k0 < 768; k0 += 32) {
    gload16(Xb + (size_t)(m0 + lrow) * 768 + k0 + lseg, As + tid * 8);
    gload16(Xb + (size_t)(m0 + 64 + lrow) * 768 + k0 + lseg, As + 2048 + tid * 8);
    __syncthreads();
    bf16x8 bv = *(const bf16x8*)(Bs + lr * 768 + k0 + lk * 8);
    bf16x8 a0 = *(const bf16x8*)(As + (wave * 32 + lr) * 32 + lk * 8);
    bf16x8 a1 = *(const bf16x8*)(As + (wave * 32 + 16 + lr) * 32 + lk * 8);
    acc0 = __builtin_amdgcn_mfma_f32_16x16x32_bf16(a0, bv, acc0, 0, 0, 0);
    acc1 = __builtin_amdgcn_mfma_f32_16x16x32_bf16(a1, bv, acc1, 0, 0, 0);
    __syncthreads();
  }
  // C/D: col(h) = lane&15, row = (lane>>4)*4 + r  (within each 16-row tile)
#pragma unroll
  for (int r = 0; r < 4; r++) {
    const int row0 = wave * 32 + lk * 4 + r;
    eS[row0 * 16 + lr] = __expf(acc0[r] * 0.125f) * mask[m0 + row0];
    const int row1 = row0 + 16;
    eS[row1 * 16 + lr] = __expf(acc1[r] * 0.125f) * mask[m0 + row1];
  }
  __syncthreads();
  if (tid < 192) {                       // parallel per-h partial sums of e
    const int h = tid >> 4, seg = tid & 15;
    float s = 0.f;
#pragma unroll
    for (int j = 0; j < 8; j++) s += eS[(seg * 8 + j) * 16 + h];
    ps[tid] = s;
  }
  __syncthreads();
  if (tid < 12) {
    float s = 0.f;
#pragma unroll
    for (int seg = 0; seg < 16; seg++) s += ps[tid * 16 + seg];
    atomicAdd(&sume[b * 12 + tid], s);
  }
  // phase 2: a[j][h] = sum_rows e[row][h] * X[row][j*256+tid]
  float a[3][12];
#pragma unroll
  for (int j = 0; j < 3; j++)
#pragma unroll
    for (int h = 0; h < 12; h++) a[j][h] = 0.f;
  for (int row = 0; row < 128; row++) {
    const f32x4* ep = (const f32x4*)(eS + row * 16);
    const f32x4 e0 = ep[0], e1 = ep[1], e2 = ep[2];
    const uint16_t* xr = Xb + (size_t)(m0 + row) * 768;
    const float x0 = bf2f(xr[tid]);
    const float x1 = bf2f(xr[256 + tid]);
    const float x2 = bf2f(xr[512 + tid]);
#pragma unroll
    for (int q = 0; q < 4; q++) {
      a[0][q]     += e0[q] * x0; a[1][q]     += e0[q] * x1; a[2][q]     += e0[q] * x2;
      a[0][4 + q] += e1[q] * x0; a[1][4 + q] += e1[q] * x1; a[2][4 + q] += e1[q] * x2;
      a[0][8 + q] += e2[q] * x0; a[1][8 + q] += e2[q] * x1; a[2][8 + q] += e2[q] * x2;
    }
  }
  float* pb = part + (size_t)bid * 9216;   // [block][h][c], plain stores
#pragma unroll
  for (int j = 0; j < 3; j++)
#pragma unroll
    for (int h = 0; h < 12; h++)
      pb[h * 768 + j * 256 + tid] = a[j][h];
}

// ---------------------------------------------------------------------------
// ctx: reduce 32 partial slabs -> sx[h][c] in LDS; then
// out[b][col] = (sx[col>>6] . W[:,col]) / (sume+eps)  (* scale[col] if k-pass)
__global__ __launch_bounds__(256) void ctx_kernel(
    const float* __restrict__ part, const float* __restrict__ sume,
    const float* __restrict__ W, const float* __restrict__ scale,
    int useScale, float* __restrict__ out) {
  __shared__ float sxS[4 * 768];           // 12 KB: 4 heads per block
  const int tid = threadIdx.x, bid = blockIdx.x;   // 24 blocks
  const int b = bid / 3, c0 = (bid % 3) * 256;
  const int h0 = c0 >> 6;
#pragma unroll
  for (int hp = 0; hp < 4; hp++)
#pragma unroll
    for (int j = 0; j < 3; j++) {
      const int c = j * 256 + tid;
      const float* pp = part + ((size_t)(b * 32) * 12 + (h0 + hp)) * 768 + c;
      float s = 0.f;
#pragma unroll 4
      for (int p = 0; p < 32; p++) s += pp[(size_t)p * 9216];
      sxS[hp * 768 + c] = s;
    }
  __syncthreads();
  const int col = c0 + tid, h = col >> 6, hl = h - h0;
  const float* sx = sxS + hl * 768;
  float acc = 0.f;
#pragma unroll 4
  for (int c = 0; c < 768; c++) acc += sx[c] * W[(size_t)c * 768 + col];
  float r = acc / (sume[b * 12 + h] + 1e-8f);
  if (useScale) r *= scale[b * 768 + col];
  out[b * 768 + col] = r;
}

// ---------------------------------------------------------------------------
// wkeff: WkeffT[b][hp][kin] = bf16( sum_c Wk[kin,c] * qctx[b,c] * Wka[c,hp] )
// using WkT (bf16) for coalesced reads; hp in [12,16) zeroed.
__global__ __launch_bounds__(256) void wkeff_kernel(
    const float* __restrict__ qctx, const float* __restrict__ Wka,
    const uint16_t* __restrict__ WkT, uint16_t* __restrict__ WkeffT) {
  __shared__ float w[768];
  const int tid = threadIdx.x;
  const int b = blockIdx.x >> 4, hp = blockIdx.x & 15;
  uint16_t* ob = WkeffT + ((size_t)b * 16 + hp) * 768;
  if (hp >= 12) {
    ob[tid] = 0; ob[256 + tid] = 0; ob[512 + tid] = 0;
    return;
  }
#pragma unroll
  for (int j = 0; j < 3; j++) {
    const int c = j * 256 + tid;
    w[c] = qctx[b * 768 + c] * Wka[c * 12 + hp];
  }
  __syncthreads();
  float a0 = 0.f, a1 = 0.f, a2 = 0.f;
#pragma unroll 4
  for (int c = 0; c < 768; c++) {
    const float wc = w[c];
    const uint16_t* row = WkT + (size_t)c * 768;
    a0 += bf2f(row[tid]) * wc;
    a1 += bf2f(row[256 + tid]) * wc;
    a2 += bf2f(row[512 + tid]) * wc;
  }
  ob[tid] = f2bf(a0); ob[256 + tid] = f2bf(a1); ob[512 + tid] = f2bf(a2);
}

// ---------------------------------------------------------------------------
// buildbt: BT_b[ngl][k] = bf16( WqT[ngl][k] + sum_d C[n][d]*WqT[h*64+d][k] ),
// C[n][d] = kctx[b, h*64+d] * Wo[d][n],  ngl = h*64+n.  96-col k-chunks.
__global__ __launch_bounds__(256) void buildbt_kernel(
    const float* __restrict__ kctx, const float* __restrict__ Wo,
    const uint16_t* __restrict__ WqT, uint16_t* __restrict__ BT) {
  __shared__ float CS[64 * 65];                   // padded: (n+d)%32 banks
  __shared__ __align__(16) uint16_t chS[64 * 96]; // 12 KB
  const int tid = threadIdx.x;
  const int kc = blockIdx.x & 7, bh = blockIdx.x >> 3;  // 768 blocks
  const int b = bh / 12, h = bh % 12;
  const int kc0 = kc * 96;
  for (int i = tid; i < 4096; i += 256) {
    const int d = i >> 6, n = i & 63;
    CS[n * 65 + d] = kctx[b * 768 + h * 64 + d] * Wo[d * 64 + n];
  }
#pragma unroll
  for (int p = 0; p < 3; p++) {
    const int cidx = p * 256 + tid;               // 0..767
    const int d = cidx / 12, kk = (cidx % 12) * 8;
    gload16(WqT + (size_t)(h * 64 + d) * 768 + kc0 + kk, chS + cidx * 8);
  }
  __syncthreads();
  const int n = tid & 63, ksub = tid >> 6;        // n = lane -> CS 2-way free
  float acc[3][8];
#pragma unroll
  for (int q = 0; q < 3; q++) {                   // self term (d == n row)
    const u16x8 v = *(const u16x8*)(chS + n * 96 + ksub * 8 + q * 32);
#pragma unroll
    for (int j = 0; j < 8; j++) acc[q][j] = bf2f(v[j]);
  }
  for (int d = 0; d < 64; d++) {
    const float cv = CS[n * 65 + d];
#pragma unroll
    for (int q = 0; q < 3; q++) {
      const u16x8 v = *(const u16x8*)(chS + d * 96 + ksub * 8 + q * 32);
#pragma unroll
      for (int j = 0; j < 8; j++) acc[q][j] += cv * bf2f(v[j]);
    }
  }
  uint16_t* ob = BT + (size_t)b * 589824 + (size_t)(h * 64 + n) * 768 + kc0 + ksub * 8;
#pragma unroll
  for (int q = 0; q < 3; q++) {
    u16x8 o;
#pragma unroll
    for (int j = 0; j < 8; j++) o[j] = f2bf(acc[q][j]);
    *(u16x8*)(ob + q * 32) = o;
  }
}

// ---------------------------------------------------------------------------
// gemm_out: out[32768x768] fp32 = Xb @ BT_b^T.  128x128 tile, 4 waves, BK=64,
// LDS XOR swizzle (inverse-swizzled DMA source + swizzled ds_read; reaches
// the 8-lanes/16B-slot floor of wave64 ds_read_b128), batch-per-XCD mapping
// (BT_b 1.1 MB stays L2-resident).
__global__ __launch_bounds__(256) void gemm_out(
    const uint16_t* __restrict__ Xb, const uint16_t* __restrict__ BT,
    float* __restrict__ out) {
  __shared__ __align__(16) uint16_t As[128 * 64];  // 16 KB
  __shared__ __align__(16) uint16_t Bs[128 * 64];  // 16 KB
  const int tid = threadIdx.x;
  const int bid = blockIdx.x;            // 1536
  const int b = bid & 7;                 // batch == XCD
  const int slot = bid >> 3;             // 0..191
  const int nblk = slot % 6;             // consecutive slots share A-strip
  const int m0 = b * 4096 + (slot / 6) * 128;
  const int cn0 = nblk * 128;
  const uint16_t* BTb = BT + (size_t)b * 589824 + (size_t)cn0 * 768;
  const int wave = tid >> 6, lane = tid & 63, lr = lane & 15, lk = lane >> 4;
  const int wm = (wave & 1) * 64, wn = (wave >> 1) * 64;
  const f32x4 zero = {0.f, 0.f, 0.f, 0.f};
  f32x4 acc[4][4];
#pragma unroll
  for (int mi = 0; mi < 4; mi++)
#pragma unroll
    for (int ni = 0; ni < 4; ni++) acc[mi][ni] = zero;
  // source permutation == read-side XOR (byte5 ^= byte9), involution
  const int tp = tid ^ ((tid >> 4) & 2);
  const int srow = tp >> 3, sseg = (tp & 7) * 8;
  for (int k0 = 0; k0 < 768; k0 += 64) {
#pragma unroll
    for (int p = 0; p < 4; p++) {
      gload16(Xb  + (size_t)(m0 + p * 32 + srow) * 768 + k0 + sseg,
              As + p * 2048 + tid * 8);
      gload16(BTb + (size_t)(p * 32 + srow) * 768 + k0 + sseg,
              Bs + p * 2048 + tid * 8);
    }
    __syncthreads();  // drains DMA before LDS reads
#pragma unroll
    for (int kk = 0; kk < 2; kk++) {
      bf16x8 af[4], bv[4];
#pragma unroll
      for (int mi = 0; mi < 4; mi++) {
        const int row = wm + mi * 16 + lr;
        const int off = (row * 64 + kk * 32 + lk * 8) ^ ((row & 4) << 2);
        af[mi] = *(const bf16x8*)(As + off);
      }
#pragma unroll
      for (int ni = 0; ni < 4; ni++) {
        const int row = wn + ni * 16 + lr;
        const int off = (row * 64 + kk * 32 + lk * 8) ^ ((row & 4) << 2);
        bv[ni] = *(const bf16x8*)(Bs + off);
      }
#pragma unroll
      for (int mi = 0; mi < 4; mi++)
#pragma unroll
        for (int ni = 0; ni < 4; ni++)
          acc[mi][ni] = __builtin_amdgcn_mfma_f32_16x16x32_bf16(
              af[mi], bv[ni], acc[mi][ni], 0, 0, 0);
    }
    __syncthreads();  // protect LDS from next iteration's DMA
  }
  // C/D layout: col = lane&15, row = (lane>>4)*4 + reg
#pragma unroll
  for (int mi = 0; mi < 4; mi++)
#pragma unroll
    for (int ni = 0; ni < 4; ni++) {
      const int col = cn0 + wn + ni * 16 + lr;
#pragma unroll
      for (int r = 0; r < 4; r++) {
        const int row = m0 + wm + mi * 16 + lk * 4 + r;
        out[(size_t)row * 768 + col] = acc[mi][ni][r];
      }
    }
}

// ---------------------------------------------------------------------------
extern "C" void kernel_launch(void* const* d_in, const int* in_sizes, int n_in,
                              void* d_out, int out_size, void* d_ws, size_t ws_size,
                              hipStream_t stream) {
  const float* x    = (const float*)d_in[0];
  const float* mask = (const float*)d_in[1];
  const float* Wq   = (const float*)d_in[2];
  const float* Wk   = (const float*)d_in[3];
  const float* Wqa  = (const float*)d_in[4];
  const float* Wka  = (const float*)d_in[5];
  const float* Wo   = (const float*)d_in[6];
  float* out = (float*)d_out;
  char* ws = (char*)d_ws;

  // workspace layout (bytes); total 81,273,856 (< proven 103.3 MB budget)
  uint16_t* Xb     = (uint16_t*)(ws);                 // 50331648
  uint16_t* WT     = (uint16_t*)(ws + 50331648);      // 2359296 (WqT|WkT bf16)
  uint16_t* WqeffT = (uint16_t*)(ws + 52690944);      // 24576
  uint16_t* WkeffT = (uint16_t*)(ws + 52715520);      // 196608
  uint16_t* BTw    = (uint16_t*)(ws + 52912128);      // 9437184
  float*    qctx   = (float*)   (ws + 62349312);      // 24576
  float*    kctx   = (float*)   (ws + 62373888);      // 24576
  float*    part_q = (float*)   (ws + 62398464);      // 9437184
  float*    part_k = (float*)   (ws + 71835648);      // 9437184
  float*    sume_q = (float*)   (ws + 81272832);      // 512
  float*    sume_k = (float*)   (ws + 81273344);      // 512

  hipMemsetAsync(sume_q, 0, 1024, stream);  // only the atomic accumulators

  prep_kernel<<<16944, 256, 0, stream>>>(x, Wq, Wk, Wqa, Xb, WT, WqeffT);
  xsum_kernel<<<256, 256, 0, stream>>>(Xb, WqeffT, mask, 0, part_q, sume_q);
  ctx_kernel<<<24, 256, 0, stream>>>(part_q, sume_q, Wq, qctx, 0, qctx);
  wkeff_kernel<<<128, 256, 0, stream>>>(qctx, Wka, WT + 589824, WkeffT);
  xsum_kernel<<<256, 256, 0, stream>>>(Xb, WkeffT, mask, 12288, part_k, sume_k);
  ctx_kernel<<<24, 256, 0, stream>>>(part_k, sume_k, Wk, qctx, 1, kctx);
  buildbt_kernel<<<768, 256, 0, stream>>>(kctx, Wo, WT, BTw);
  gemm_out<<<1536, 256, 0, stream>>>(Xb, BTw, out);
}

// Round 6
// 354.252 us; speedup vs baseline: 1.8547x; 1.8547x over previous
//
#include <hip/hip_runtime.h>
#include <stdint.h>

// ---------------------------------------------------------------------------
// Fastformer fused pipeline, MI355X gfx950.  Round 10: SAFE LANE.
// Base = round-4 baseline (365.7 us, repeatedly harness-passing) with exactly
// two surgical upgrades, both taken from code proven in the r6 pass:
//  (1) prep job1: LDS-tiled coalesced W transpose (was stride-3072 scatter,
//      one 64B sector per element -> 113 us; now coalesced both sides)
//  (2) gemm_qk: inner loop transplanted from the r6-proven gemm_out
//      (BK=64, XOR-swizzled DMA source + swizzled ds_read) -> kills the
//      9.4M LDS bank conflicts measured at round 0
// scoresum / ctxkaeff / out_kernel / workspace / launches byte-identical to
// the 365.7 us baseline.  (Collapse pipeline shelved: 1 pass / 5 attempts
// with zero source-content signal -> infra experiment; this round banks a
// win AND tests the infra with maximally-proven code.)
// ---------------------------------------------------------------------------

#define AS1 __attribute__((address_space(1)))
#define AS3 __attribute__((address_space(3)))

typedef __attribute__((ext_vector_type(8))) __bf16   bf16x8;
typedef __attribute__((ext_vector_type(8))) uint16_t u16x8;
typedef __attribute__((ext_vector_type(4))) float    f32x4;

__device__ __forceinline__ float bf2f(uint16_t v) {
  union { uint32_t u; float f; } x; x.u = ((uint32_t)v) << 16; return x.f;
}
__device__ __forceinline__ uint16_t f2bf(float f) {
  uint32_t u = __float_as_uint(f);
  uint32_t r = (u + 0x7fffu + ((u >> 16) & 1u)) >> 16;
  return (uint16_t)r;
}
__device__ __forceinline__ bf16x8 cvt8(const float4 lo, const float4 hi) {
  u16x8 r;
  r[0] = f2bf(lo.x); r[1] = f2bf(lo.y); r[2] = f2bf(lo.z); r[3] = f2bf(lo.w);
  r[4] = f2bf(hi.x); r[5] = f2bf(hi.y); r[6] = f2bf(hi.z); r[7] = f2bf(hi.w);
  union { u16x8 u; bf16x8 b; } c; c.u = r; return c.b;
}
// async global->LDS, 16 B/lane; LDS dest must be lane-contiguous (tid*16B).
__device__ __forceinline__ void gload16(const void* g, void* l) {
  __builtin_amdgcn_global_load_lds((AS1 void*)(void*)g, (AS3 void*)l, 16, 0, 0);
}

// ---------------------------------------------------------------------------
// prep: job0 cvt X->Xb (12288 blocks)
//       job1 WT = bf16(Wq^T|Wk^T) via 64x64 LDS tiles (288 blocks)
//       job2 WqaT[hp][k] = bf16(Wqa[k][hp]) (48 blocks)  [r4 verbatim]
__global__ __launch_bounds__(256) void prep_kernel(
    const float* __restrict__ X, const float* __restrict__ Wq,
    const float* __restrict__ Wk, const float* __restrict__ Wqa,
    uint16_t* __restrict__ Xb, uint16_t* __restrict__ WT,
    uint16_t* __restrict__ WqaT) {
  __shared__ float T[64 * 65];   // +1 pad: conflict-free transpose
  const int bid = blockIdx.x, tid = threadIdx.x;
  if (bid < 12288) {
    size_t i = ((size_t)bid * 256 + tid) * 8;
    const float* p = X + i;
    *(bf16x8*)(Xb + i) = cvt8(*(const float4*)p, *(const float4*)(p + 4));
  } else if (bid < 12576) {
    const int idx = bid - 12288;                // 0..287
    const int m = idx / 144, t = idx - m * 144; // 2 matrices x 144 tiles
    const int tn = t % 12, tk = t / 12;
    const float* src = m ? Wk : Wq;
    uint16_t* dst = WT + (size_t)m * 589824;
    const int quad = tid >> 6, ln = tid & 63;
#pragma unroll
    for (int r = 0; r < 16; r++) {
      const int kl = quad * 16 + r;             // coalesced 256B row reads
      T[kl * 65 + ln] = src[(size_t)(tk * 64 + kl) * 768 + tn * 64 + ln];
    }
    __syncthreads();
#pragma unroll
    for (int r = 0; r < 16; r++) {
      const int nl = quad * 16 + r;             // coalesced 128B row writes
      dst[(size_t)(tn * 64 + nl) * 768 + tk * 64 + ln] = f2bf(T[ln * 65 + nl]);
    }
  } else {
    int i = (bid - 12576) * 256 + tid;          // 0..12287
    int hp = i / 768, k = i - hp * 768;
    WqaT[i] = (hp < 12) ? f2bf(Wqa[k * 12 + hp]) : (uint16_t)0;
  }
}

// ---------------------------------------------------------------------------
// gemm: C[32768 x 1536] = Xb @ WT^T, bf16 out split Qb/Kb.  128x128 block,
// 4 waves x (64x64), BK=64, XOR-swizzled staging + swizzled ds_read (loop
// body transplanted from the r6-proven gemm_out), r4-proven XCD swizzle.
__global__ __launch_bounds__(256) void gemm_qk(
    const uint16_t* __restrict__ Xb, const uint16_t* __restrict__ WT,
    uint16_t* __restrict__ Qb, uint16_t* __restrict__ Kb) {
  __shared__ __align__(16) uint16_t As[128 * 64];  // 16 KB
  __shared__ __align__(16) uint16_t Bs[128 * 64];  // 16 KB
  const int tid = threadIdx.x;
  // swizzle: same-m0 column blocks -> same XCD (bid%8), consecutive slots
  const int bid = blockIdx.x;              // 0..3071
  const int xr = bid & 7, th = bid >> 3;   // th: 0..383
  const int nblk = th % 12;
  const int m0 = ((th / 12) * 8 + xr) * 128;
  const uint16_t* BT = WT + (size_t)nblk * 98304;
  uint16_t* C   = (nblk < 6) ? Qb : Kb;
  const int cn0 = ((nblk < 6) ? nblk : nblk - 6) * 128;

  const int wave = tid >> 6, lane = tid & 63, lr = lane & 15, lk = lane >> 4;
  const int wm = (wave & 1) * 64, wn = (wave >> 1) * 64;
  const f32x4 zero = {0.f, 0.f, 0.f, 0.f};
  f32x4 acc[4][4];
#pragma unroll
  for (int mi = 0; mi < 4; mi++)
#pragma unroll
    for (int ni = 0; ni < 4; ni++) acc[mi][ni] = zero;
  // source permutation == read-side XOR (byte5 ^= byte9), involution
  const int tp = tid ^ ((tid >> 4) & 2);
  const int srow = tp >> 3, sseg = (tp & 7) * 8;
  for (int k0 = 0; k0 < 768; k0 += 64) {
#pragma unroll
    for (int p = 0; p < 4; p++) {
      gload16(Xb + (size_t)(m0 + p * 32 + srow) * 768 + k0 + sseg,
              As + p * 2048 + tid * 8);
      gload16(BT + (size_t)(p * 32 + srow) * 768 + k0 + sseg,
              Bs + p * 2048 + tid * 8);
    }
    __syncthreads();  // drains DMA before LDS reads
#pragma unroll
    for (int kk = 0; kk < 2; kk++) {
      bf16x8 af[4], bv[4];
#pragma unroll
      for (int mi = 0; mi < 4; mi++) {
        const int row = wm + mi * 16 + lr;
        const int off = (row * 64 + kk * 32 + lk * 8) ^ ((row & 4) << 2);
        af[mi] = *(const bf16x8*)(As + off);
      }
#pragma unroll
      for (int ni = 0; ni < 4; ni++) {
        const int row = wn + ni * 16 + lr;
        const int off = (row * 64 + kk * 32 + lk * 8) ^ ((row & 4) << 2);
        bv[ni] = *(const bf16x8*)(Bs + off);
      }
#pragma unroll
      for (int mi = 0; mi < 4; mi++)
#pragma unroll
        for (int ni = 0; ni < 4; ni++)
          acc[mi][ni] = __builtin_amdgcn_mfma_f32_16x16x32_bf16(
              af[mi], bv[ni], acc[mi][ni], 0, 0, 0);
    }
    __syncthreads();  // protect LDS from next iteration's DMA
  }
  // C/D layout: col = lane&15, row = (lane>>4)*4 + reg
#pragma unroll
  for (int mi = 0; mi < 4; mi++)
#pragma unroll
    for (int ni = 0; ni < 4; ni++) {
      const int col = cn0 + wn + ni * 16 + lr;
#pragma unroll
      for (int r = 0; r < 4; r++) {
        const int row = m0 + wm + mi * 16 + lk * 4 + r;
        C[(size_t)row * 768 + col] = f2bf(acc[mi][ni][r]);
      }
    }
}

// ---------------------------------------------------------------------------
// scoresum: per 64-row block. Phase 1: scores = A @ BT^T (MFMA, N=16),
// e = exp(s/8)*mask into LDS. Phase 2: sumv[b][col] += e*A, sume[b][h] += e.
// [r4 verbatim]
__global__ __launch_bounds__(256) void scoresum_kernel(
    const uint16_t* __restrict__ A,      // 32768x768 bf16 (Qb or Kb); also V
    const uint16_t* __restrict__ BT,     // [16][768] bf16 (+bStride per batch)
    const float* __restrict__ mask,
    int bStride,
    float* __restrict__ sumv, float* __restrict__ sume) {
  __shared__ __align__(16) uint16_t Bs[16 * 768];  // 24 KB
  __shared__ __align__(16) uint16_t As[64 * 32];   // 4 KB
  __shared__ float eS[64 * 16];                    // 4 KB
  const int tid = threadIdx.x;
  const int m0  = blockIdx.x * 64;
  const int b   = m0 >> 12;
  const uint16_t* BTb = BT + (size_t)b * bStride;
#pragma unroll
  for (int p = 0; p < 6; p++)
    gload16(BTb + (size_t)(p * 256 + tid) * 8, Bs + (p * 256 + tid) * 8);
  const int wave = tid >> 6, lane = tid & 63, lr = lane & 15, lk = lane >> 4;
  const f32x4 zero = {0.f, 0.f, 0.f, 0.f};
  f32x4 acc = zero;
  const int lrow = tid >> 2, lseg = (tid & 3) * 8;
  for (int k0 = 0; k0 < 768; k0 += 32) {
    gload16(A + (size_t)(m0 + lrow) * 768 + k0 + lseg, As + tid * 8);
    __syncthreads();
    bf16x8 af  = *(const bf16x8*)(As + (wave * 16 + lr) * 32 + lk * 8);
    bf16x8 bfv = *(const bf16x8*)(Bs + lr * 768 + k0 + lk * 8);
    acc = __builtin_amdgcn_mfma_f32_16x16x32_bf16(af, bfv, acc, 0, 0, 0);
    __syncthreads();
  }
  // e into LDS: row = wave*16 + lk*4 + r, col(h) = lr
#pragma unroll
  for (int r = 0; r < 4; r++) {
    const int row = wave * 16 + lk * 4 + r;
    eS[row * 16 + lr] = __expf(acc[r] * 0.125f) * mask[m0 + row];
  }
  __syncthreads();
  if (tid < 12) {  // per-h partial sum of e
    float s = 0.f;
    for (int r = 0; r < 64; r++) s += eS[r * 16 + tid];
    atomicAdd(&sume[b * 12 + tid], s);
  }
  // weighted sums: cols {tid, 256+tid, 512+tid}; h = p*4 + wave (uniform)
  float a0 = 0.f, a1 = 0.f, a2 = 0.f;
  const uint16_t* V = A + (size_t)m0 * 768;
  for (int row = 0; row < 64; row++) {
    const uint16_t* Vr = V + (size_t)row * 768;
    const float* er = eS + row * 16;
    a0 += er[wave]     * bf2f(Vr[tid]);
    a1 += er[4 + wave] * bf2f(Vr[256 + tid]);
    a2 += er[8 + wave] * bf2f(Vr[512 + tid]);
  }
  atomicAdd(&sumv[b * 768 + tid],       a0);
  atomicAdd(&sumv[b * 768 + 256 + tid], a1);
  atomicAdd(&sumv[b * 768 + 512 + tid], a2);
}

// ---------------------------------------------------------------------------
// ctxkaeff: qctx = sumeq/(sume+eps); WkaT[b][hp][k] = bf16(qctx*Wka[k][hp])
// [r4 verbatim]
__global__ __launch_bounds__(256) void ctxkaeff_kernel(
    const float* __restrict__ sumeq, const float* __restrict__ sume,
    const float* __restrict__ Wka, uint16_t* __restrict__ WkaT,
    float* __restrict__ qctx) {
  int i = blockIdx.x * 256 + threadIdx.x;  // 8*16*768
  int k = i % 768, hp = (i / 768) & 15, b = i / 12288;
  float qc = sumeq[b * 768 + k] / (sume[b * 12 + (k >> 6)] + 1e-8f);
  WkaT[i] = (hp < 12) ? f2bf(qc * Wka[k * 12 + hp]) : (uint16_t)0;
  if (hp == 0) qctx[b * 768 + k] = qc;
}

// ---------------------------------------------------------------------------
// out: per (bh, 128-row block): Ms[n][d] = bf16(kc[d]*Wo[d][n]) computed
// in-block; out = Q + Qh @ Ms^T (fp32 store).  [r4 verbatim]
__global__ __launch_bounds__(256) void out_kernel(
    const uint16_t* __restrict__ Qb,
    const float* __restrict__ qctx, const float* __restrict__ sumv2,
    const float* __restrict__ sume2, const float* __restrict__ Wo,
    float* __restrict__ out) {
  __shared__ __align__(16) uint16_t Qs[128 * 64];  // 16 KB
  __shared__ __align__(16) uint16_t Ms[64 * 64];   // 8 KB
  __shared__ float kcS[64];
  const int tid = threadIdx.x;
  const int bh = blockIdx.x, rb = blockIdx.y;
  const int b = bh / 12, h = bh - b * 12;
  const size_t rowbase = (size_t)b * 4096 + rb * 128;
  const uint16_t* Aptr = Qb + rowbase * 768 + h * 64;
#pragma unroll
  for (int p = 0; p < 4; p++) {
    const int c = p * 256 + tid;
    gload16(Aptr + (size_t)(c >> 3) * 768 + (c & 7) * 8, Qs + c * 8);
  }
  if (tid < 64) {
    const int hd = h * 64 + tid;
    kcS[tid] = qctx[b * 768 + hd] * sumv2[b * 768 + hd] /
               (sume2[b * 12 + h] + 1e-8f);
  }
  __syncthreads();  // kcS ready (also drains Qs DMA)
#pragma unroll
  for (int p = 0; p < 16; p++) {
    const int i = p * 256 + tid;
    const int d = i & 63, n = i >> 6;
    Ms[i] = f2bf(kcS[d] * Wo[d * 64 + n]);
  }
  __syncthreads();  // Ms + Qs visible
  const int wave = tid >> 6, lane = tid & 63, lr = lane & 15, lk = lane >> 4;
  const f32x4 zero = {0.f, 0.f, 0.f, 0.f};
  f32x4 acc[2][4];
#pragma unroll
  for (int mi = 0; mi < 2; mi++)
#pragma unroll
    for (int ni = 0; ni < 4; ni++) acc[mi][ni] = zero;
#pragma unroll
  for (int kc = 0; kc < 2; kc++) {
    bf16x8 af[2], bfv[4];
#pragma unroll
    for (int mi = 0; mi < 2; mi++)
      af[mi] = *(const bf16x8*)(Qs + (wave * 32 + mi * 16 + lr) * 64 + kc * 32 + lk * 8);
#pragma unroll
    for (int ni = 0; ni < 4; ni++)
      bfv[ni] = *(const bf16x8*)(Ms + (ni * 16 + lr) * 64 + kc * 32 + lk * 8);
#pragma unroll
    for (int mi = 0; mi < 2; mi++)
#pragma unroll
      for (int ni = 0; ni < 4; ni++)
        acc[mi][ni] = __builtin_amdgcn_mfma_f32_16x16x32_bf16(
            af[mi], bfv[ni], acc[mi][ni], 0, 0, 0);
  }
#pragma unroll
  for (int mi = 0; mi < 2; mi++)
#pragma unroll
    for (int ni = 0; ni < 4; ni++)
#pragma unroll
      for (int r = 0; r < 4; r++) {
        const int row = wave * 32 + mi * 16 + lk * 4 + r;
        const int col = ni * 16 + lr;
        const float q = bf2f(Qs[row * 64 + col]);
        out[(rowbase + row) * 768 + h * 64 + col] = q + acc[mi][ni][r];
      }
}

// ---------------------------------------------------------------------------
extern "C" void kernel_launch(void* const* d_in, const int* in_sizes, int n_in,
                              void* d_out, int out_size, void* d_ws, size_t ws_size,
                              hipStream_t stream) {
  const float* x    = (const float*)d_in[0];
  const float* mask = (const float*)d_in[1];
  const float* Wq   = (const float*)d_in[2];
  const float* Wk   = (const float*)d_in[3];
  const float* Wqa  = (const float*)d_in[4];
  const float* Wka  = (const float*)d_in[5];
  const float* Wo   = (const float*)d_in[6];
  float* out = (float*)d_out;
  char* ws = (char*)d_ws;

  // Xb (bf16 x) lives in d_out's first 50 MB — dead by the time out_kernel
  // writes. out_size = 25165824 fp32 = 100.7 MB >= 50.4 MB needed.
  uint16_t* Xb = (uint16_t*)d_out;

  // workspace layout (bytes); total ~103.3 MB (proven budget)
  uint16_t* Qb    = (uint16_t*)(ws);                    // 50331648
  uint16_t* Kb    = (uint16_t*)(ws + 50331648);         // 50331648
  uint16_t* WT    = (uint16_t*)(ws + 100663296);        // 2359296
  uint16_t* WqaT  = (uint16_t*)(ws + 103022592);        // 24576
  uint16_t* WkaT  = (uint16_t*)(ws + 103047168);        // 196608
  float*    accum = (float*)   (ws + 103243776);        // 49920
  float* sume   = accum;               // 96
  float* sume2  = accum + 96;          // 96
  float* sumeq  = accum + 192;         // 6144
  float* sume2k = accum + 192 + 6144;  // 6144
  float* qctx   = (float*)(ws + 103293696);             // 24576

  hipMemsetAsync(accum, 0, 12480 * sizeof(float), stream);

  prep_kernel<<<12624, 256, 0, stream>>>(x, Wq, Wk, Wqa, Xb, WT, WqaT);
  gemm_qk<<<3072, 256, 0, stream>>>(Xb, WT, Qb, Kb);
  scoresum_kernel<<<512, 256, 0, stream>>>(Qb, WqaT, mask, 0, sumeq, sume);
  ctxkaeff_kernel<<<384, 256, 0, stream>>>(sumeq, sume, Wka, WkaT, qctx);
  scoresum_kernel<<<512, 256, 0, stream>>>(Kb, WkaT, mask, 12288, sume2k, sume2);
  out_kernel<<<dim3(96, 32), 256, 0, stream>>>(Qb, qctx, sume2k, sume2, Wo, out);
}

// Round 7
// 348.154 us; speedup vs baseline: 1.8872x; 1.0175x over previous
//
#include <hip/hip_runtime.h>
#include <stdint.h>

// ---------------------------------------------------------------------------
// Fastformer fused pipeline, MI355X gfx950.  Round 11: safe lane, swizzle
// actually fixed.  Round-10's ^((row&4)<<2) was a slot RELABELING, not a
// spread (SQ_LDS_BANK_CONFLICT identical 9437184 to round 0 = proof).
// Correct form: slot ^= row&7  ->  element_off ^ ((row&7)<<3), source
// segment seg ^ (row&7).  Uniform 8 lanes/16B-slot = wave64 b128 floor.
// Changes vs the 354.3 us round-10 pass:
//  (1) gemm_qk: corrected XOR swizzle (both sides)
//  (2) scoresum: BK=64 (half the barriers) + corrected swizzle on A AND B
//      (B's [16][768] rows are 0 mod 8 slots -> was also 16-way conflicted)
// prep / ctxkaeff / out_kernel / workspace / launches byte-identical.
// ---------------------------------------------------------------------------

#define AS1 __attribute__((address_space(1)))
#define AS3 __attribute__((address_space(3)))

typedef __attribute__((ext_vector_type(8))) __bf16   bf16x8;
typedef __attribute__((ext_vector_type(8))) uint16_t u16x8;
typedef __attribute__((ext_vector_type(4))) float    f32x4;

__device__ __forceinline__ float bf2f(uint16_t v) {
  union { uint32_t u; float f; } x; x.u = ((uint32_t)v) << 16; return x.f;
}
__device__ __forceinline__ uint16_t f2bf(float f) {
  uint32_t u = __float_as_uint(f);
  uint32_t r = (u + 0x7fffu + ((u >> 16) & 1u)) >> 16;
  return (uint16_t)r;
}
__device__ __forceinline__ bf16x8 cvt8(const float4 lo, const float4 hi) {
  u16x8 r;
  r[0] = f2bf(lo.x); r[1] = f2bf(lo.y); r[2] = f2bf(lo.z); r[3] = f2bf(lo.w);
  r[4] = f2bf(hi.x); r[5] = f2bf(hi.y); r[6] = f2bf(hi.z); r[7] = f2bf(hi.w);
  union { u16x8 u; bf16x8 b; } c; c.u = r; return c.b;
}
// async global->LDS, 16 B/lane; LDS dest must be lane-contiguous (tid*16B).
__device__ __forceinline__ void gload16(const void* g, void* l) {
  __builtin_amdgcn_global_load_lds((AS1 void*)(void*)g, (AS3 void*)l, 16, 0, 0);
}

// ---------------------------------------------------------------------------
// prep: job0 cvt X->Xb (12288 blocks)
//       job1 WT = bf16(Wq^T|Wk^T) via 64x64 LDS tiles (288 blocks)
//       job2 WqaT[hp][k] = bf16(Wqa[k][hp]) (48 blocks)   [r10 verbatim]
__global__ __launch_bounds__(256) void prep_kernel(
    const float* __restrict__ X, const float* __restrict__ Wq,
    const float* __restrict__ Wk, const float* __restrict__ Wqa,
    uint16_t* __restrict__ Xb, uint16_t* __restrict__ WT,
    uint16_t* __restrict__ WqaT) {
  __shared__ float T[64 * 65];   // +1 pad: conflict-free transpose
  const int bid = blockIdx.x, tid = threadIdx.x;
  if (bid < 12288) {
    size_t i = ((size_t)bid * 256 + tid) * 8;
    const float* p = X + i;
    *(bf16x8*)(Xb + i) = cvt8(*(const float4*)p, *(const float4*)(p + 4));
  } else if (bid < 12576) {
    const int idx = bid - 12288;                // 0..287
    const int m = idx / 144, t = idx - m * 144; // 2 matrices x 144 tiles
    const int tn = t % 12, tk = t / 12;
    const float* src = m ? Wk : Wq;
    uint16_t* dst = WT + (size_t)m * 589824;
    const int quad = tid >> 6, ln = tid & 63;
#pragma unroll
    for (int r = 0; r < 16; r++) {
      const int kl = quad * 16 + r;             // coalesced 256B row reads
      T[kl * 65 + ln] = src[(size_t)(tk * 64 + kl) * 768 + tn * 64 + ln];
    }
    __syncthreads();
#pragma unroll
    for (int r = 0; r < 16; r++) {
      const int nl = quad * 16 + r;             // coalesced 128B row writes
      dst[(size_t)(tn * 64 + nl) * 768 + tk * 64 + ln] = f2bf(T[ln * 65 + nl]);
    }
  } else {
    int i = (bid - 12576) * 256 + tid;          // 0..12287
    int hp = i / 768, k = i - hp * 768;
    WqaT[i] = (hp < 12) ? f2bf(Wqa[k * 12 + hp]) : (uint16_t)0;
  }
}

// ---------------------------------------------------------------------------
// gemm: C[32768 x 1536] = Xb @ WT^T, bf16 out split Qb/Kb.  128x128 block,
// 4 waves x (64x64), BK=64, CORRECT row&7 XOR swizzle (source + read).
__global__ __launch_bounds__(256) void gemm_qk(
    const uint16_t* __restrict__ Xb, const uint16_t* __restrict__ WT,
    uint16_t* __restrict__ Qb, uint16_t* __restrict__ Kb) {
  __shared__ __align__(16) uint16_t As[128 * 64];  // 16 KB
  __shared__ __align__(16) uint16_t Bs[128 * 64];  // 16 KB
  const int tid = threadIdx.x;
  // swizzle: same-m0 column blocks -> same XCD (bid%8), consecutive slots
  const int bid = blockIdx.x;              // 0..3071
  const int xr = bid & 7, th = bid >> 3;   // th: 0..383
  const int nblk = th % 12;
  const int m0 = ((th / 12) * 8 + xr) * 128;
  const uint16_t* BT = WT + (size_t)nblk * 98304;
  uint16_t* C   = (nblk < 6) ? Qb : Kb;
  const int cn0 = ((nblk < 6) ? nblk : nblk - 6) * 128;

  const int wave = tid >> 6, lane = tid & 63, lr = lane & 15, lk = lane >> 4;
  const int wm = (wave & 1) * 64, wn = (wave >> 1) * 64;
  const f32x4 zero = {0.f, 0.f, 0.f, 0.f};
  f32x4 acc[4][4];
#pragma unroll
  for (int mi = 0; mi < 4; mi++)
#pragma unroll
    for (int ni = 0; ni < 4; ni++) acc[mi][ni] = zero;
  // source permutation: unit tid holds (row=tid>>3, seg=(tid&7)^(row&7));
  // read XOR ((row&7)<<3) undoes it -> 8 lanes/16B-slot (b128 floor)
  const int srow = tid >> 3;
  const int sseg = ((tid & 7) ^ (srow & 7)) * 8;
  for (int k0 = 0; k0 < 768; k0 += 64) {
#pragma unroll
    for (int p = 0; p < 4; p++) {
      gload16(Xb + (size_t)(m0 + p * 32 + srow) * 768 + k0 + sseg,
              As + p * 2048 + tid * 8);
      gload16(BT + (size_t)(p * 32 + srow) * 768 + k0 + sseg,
              Bs + p * 2048 + tid * 8);
    }
    __syncthreads();  // drains DMA before LDS reads
#pragma unroll
    for (int kk = 0; kk < 2; kk++) {
      bf16x8 af[4], bv[4];
#pragma unroll
      for (int mi = 0; mi < 4; mi++) {
        const int row = wm + mi * 16 + lr;
        const int off = (row * 64 + kk * 32 + lk * 8) ^ ((row & 7) << 3);
        af[mi] = *(const bf16x8*)(As + off);
      }
#pragma unroll
      for (int ni = 0; ni < 4; ni++) {
        const int row = wn + ni * 16 + lr;
        const int off = (row * 64 + kk * 32 + lk * 8) ^ ((row & 7) << 3);
        bv[ni] = *(const bf16x8*)(Bs + off);
      }
#pragma unroll
      for (int mi = 0; mi < 4; mi++)
#pragma unroll
        for (int ni = 0; ni < 4; ni++)
          acc[mi][ni] = __builtin_amdgcn_mfma_f32_16x16x32_bf16(
              af[mi], bv[ni], acc[mi][ni], 0, 0, 0);
    }
    __syncthreads();  // protect LDS from next iteration's DMA
  }
  // C/D layout: col = lane&15, row = (lane>>4)*4 + reg
#pragma unroll
  for (int mi = 0; mi < 4; mi++)
#pragma unroll
    for (int ni = 0; ni < 4; ni++) {
      const int col = cn0 + wn + ni * 16 + lr;
#pragma unroll
      for (int r = 0; r < 4; r++) {
        const int row = m0 + wm + mi * 16 + lk * 4 + r;
        C[(size_t)row * 768 + col] = f2bf(acc[mi][ni][r]);
      }
    }
}

// ---------------------------------------------------------------------------
// scoresum: per 64-row block. Phase 1: scores = A @ BT^T (MFMA, N=16),
// BK=64, swizzled A ([64][64]) AND B ([16][768], seg ^= row&7);
// e = exp(s/8)*mask into LDS. Phase 2: sumv += e*A, sume += e  [r10 verbatim]
__global__ __launch_bounds__(256) void scoresum_kernel(
    const uint16_t* __restrict__ A,      // 32768x768 bf16 (Qb or Kb); also V
    const uint16_t* __restrict__ BT,     // [16][768] bf16 (+bStride per batch)
    const float* __restrict__ mask,
    int bStride,
    float* __restrict__ sumv, float* __restrict__ sume) {
  __shared__ __align__(16) uint16_t Bs[16 * 768];  // 24 KB
  __shared__ __align__(16) uint16_t As[64 * 64];   // 8 KB
  __shared__ float eS[64 * 16];                    // 4 KB
  const int tid = threadIdx.x;
  const int m0  = blockIdx.x * 64;
  const int b   = m0 >> 12;
  const uint16_t* BTb = BT + (size_t)b * bStride;
  // Bs staged with seg^(row&7) source permutation (row = i/96, seg = i%96)
#pragma unroll
  for (int p = 0; p < 6; p++) {
    const int i = p * 256 + tid;                 // 0..1535 16B units
    const int r = i / 96, sg = i - r * 96;
    const int sg2 = (sg & ~7) | ((sg & 7) ^ (r & 7));
    gload16(BTb + (size_t)r * 768 + sg2 * 8, Bs + i * 8);
  }
  const int wave = tid >> 6, lane = tid & 63, lr = lane & 15, lk = lane >> 4;
  const f32x4 zero = {0.f, 0.f, 0.f, 0.f};
  f32x4 acc = zero;
  const int srow = tid >> 3;
  const int sseg = ((tid & 7) ^ (srow & 7)) * 8;
  const int arow = wave * 16 + lr;
  for (int k0 = 0; k0 < 768; k0 += 64) {
#pragma unroll
    for (int p = 0; p < 2; p++)
      gload16(A + (size_t)(m0 + p * 32 + srow) * 768 + k0 + sseg,
              As + p * 2048 + tid * 8);
    __syncthreads();
#pragma unroll
    for (int kk = 0; kk < 2; kk++) {
      const int aoff = (arow * 64 + kk * 32 + lk * 8) ^ ((arow & 7) << 3);
      bf16x8 af = *(const bf16x8*)(As + aoff);
      const int boff = (lr * 768 + k0 + kk * 32 + lk * 8) ^ ((lr & 7) << 3);
      bf16x8 bfv = *(const bf16x8*)(Bs + boff);
      acc = __builtin_amdgcn_mfma_f32_16x16x32_bf16(af, bfv, acc, 0, 0, 0);
    }
    __syncthreads();
  }
  // e into LDS: row = wave*16 + lk*4 + r, col(h) = lr
#pragma unroll
  for (int r = 0; r < 4; r++) {
    const int row = wave * 16 + lk * 4 + r;
    eS[row * 16 + lr] = __expf(acc[r] * 0.125f) * mask[m0 + row];
  }
  __syncthreads();
  if (tid < 12) {  // per-h partial sum of e
    float s = 0.f;
    for (int r = 0; r < 64; r++) s += eS[r * 16 + tid];
    atomicAdd(&sume[b * 12 + tid], s);
  }
  // weighted sums: cols {tid, 256+tid, 512+tid}; h = p*4 + wave (uniform)
  float a0 = 0.f, a1 = 0.f, a2 = 0.f;
  const uint16_t* V = A + (size_t)m0 * 768;
  for (int row = 0; row < 64; row++) {
    const uint16_t* Vr = V + (size_t)row * 768;
    const float* er = eS + row * 16;
    a0 += er[wave]     * bf2f(Vr[tid]);
    a1 += er[4 + wave] * bf2f(Vr[256 + tid]);
    a2 += er[8 + wave] * bf2f(Vr[512 + tid]);
  }
  atomicAdd(&sumv[b * 768 + tid],       a0);
  atomicAdd(&sumv[b * 768 + 256 + tid], a1);
  atomicAdd(&sumv[b * 768 + 512 + tid], a2);
}

// ---------------------------------------------------------------------------
// ctxkaeff: qctx = sumeq/(sume+eps); WkaT[b][hp][k] = bf16(qctx*Wka[k][hp])
// [r10 verbatim]
__global__ __launch_bounds__(256) void ctxkaeff_kernel(
    const float* __restrict__ sumeq, const float* __restrict__ sume,
    const float* __restrict__ Wka, uint16_t* __restrict__ WkaT,
    float* __restrict__ qctx) {
  int i = blockIdx.x * 256 + threadIdx.x;  // 8*16*768
  int k = i % 768, hp = (i / 768) & 15, b = i / 12288;
  float qc = sumeq[b * 768 + k] / (sume[b * 12 + (k >> 6)] + 1e-8f);
  WkaT[i] = (hp < 12) ? f2bf(qc * Wka[k * 12 + hp]) : (uint16_t)0;
  if (hp == 0) qctx[b * 768 + k] = qc;
}

// ---------------------------------------------------------------------------
// out: per (bh, 128-row block): Ms[n][d] = bf16(kc[d]*Wo[d][n]) computed
// in-block; out = Q + Qh @ Ms^T (fp32 store).  [r10 verbatim]
__global__ __launch_bounds__(256) void out_kernel(
    const uint16_t* __restrict__ Qb,
    const float* __restrict__ qctx, const float* __restrict__ sumv2,
    const float* __restrict__ sume2, const float* __restrict__ Wo,
    float* __restrict__ out) {
  __shared__ __align__(16) uint16_t Qs[128 * 64];  // 16 KB
  __shared__ __align__(16) uint16_t Ms[64 * 64];   // 8 KB
  __shared__ float kcS[64];
  const int tid = threadIdx.x;
  const int bh = blockIdx.x, rb = blockIdx.y;
  const int b = bh / 12, h = bh - b * 12;
  const size_t rowbase = (size_t)b * 4096 + rb * 128;
  const uint16_t* Aptr = Qb + rowbase * 768 + h * 64;
#pragma unroll
  for (int p = 0; p < 4; p++) {
    const int c = p * 256 + tid;
    gload16(Aptr + (size_t)(c >> 3) * 768 + (c & 7) * 8, Qs + c * 8);
  }
  if (tid < 64) {
    const int hd = h * 64 + tid;
    kcS[tid] = qctx[b * 768 + hd] * sumv2[b * 768 + hd] /
               (sume2[b * 12 + h] + 1e-8f);
  }
  __syncthreads();  // kcS ready (also drains Qs DMA)
#pragma unroll
  for (int p = 0; p < 16; p++) {
    const int i = p * 256 + tid;
    const int d = i & 63, n = i >> 6;
    Ms[i] = f2bf(kcS[d] * Wo[d * 64 + n]);
  }
  __syncthreads();  // Ms + Qs visible
  const int wave = tid >> 6, lane = tid & 63, lr = lane & 15, lk = lane >> 4;
  const f32x4 zero = {0.f, 0.f, 0.f, 0.f};
  f32x4 acc[2][4];
#pragma unroll
  for (int mi = 0; mi < 2; mi++)
#pragma unroll
    for (int ni = 0; ni < 4; ni++) acc[mi][ni] = zero;
#pragma unroll
  for (int kc = 0; kc < 2; kc++) {
    bf16x8 af[2], bfv[4];
#pragma unroll
    for (int mi = 0; mi < 2; mi++)
      af[mi] = *(const bf16x8*)(Qs + (wave * 32 + mi * 16 + lr) * 64 + kc * 32 + lk * 8);
#pragma unroll
    for (int ni = 0; ni < 4; ni++)
      bfv[ni] = *(const bf16x8*)(Ms + (ni * 16 + lr) * 64 + kc * 32 + lk * 8);
#pragma unroll
    for (int mi = 0; mi < 2; mi++)
#pragma unroll
      for (int ni = 0; ni < 4; ni++)
        acc[mi][ni] = __builtin_amdgcn_mfma_f32_16x16x32_bf16(
            af[mi], bfv[ni], acc[mi][ni], 0, 0, 0);
  }
#pragma unroll
  for (int mi = 0; mi < 2; mi++)
#pragma unroll
    for (int ni = 0; ni < 4; ni++)
#pragma unroll
      for (int r = 0; r < 4; r++) {
        const int row = wave * 32 + mi * 16 + lk * 4 + r;
        const int col = ni * 16 + lr;
        const float q = bf2f(Qs[row * 64 + col]);
        out[(rowbase + row) * 768 + h * 64 + col] = q + acc[mi][ni][r];
      }
}

// ---------------------------------------------------------------------------
extern "C" void kernel_launch(void* const* d_in, const int* in_sizes, int n_in,
                              void* d_out, int out_size, void* d_ws, size_t ws_size,
                              hipStream_t stream) {
  const float* x    = (const float*)d_in[0];
  const float* mask = (const float*)d_in[1];
  const float* Wq   = (const float*)d_in[2];
  const float* Wk   = (const float*)d_in[3];
  const float* Wqa  = (const float*)d_in[4];
  const float* Wka  = (const float*)d_in[5];
  const float* Wo   = (const float*)d_in[6];
  float* out = (float*)d_out;
  char* ws = (char*)d_ws;

  // Xb (bf16 x) lives in d_out's first 50 MB — dead by the time out_kernel
  // writes. out_size = 25165824 fp32 = 100.7 MB >= 50.4 MB needed.
  uint16_t* Xb = (uint16_t*)d_out;

  // workspace layout (bytes); total ~103.3 MB (proven budget)
  uint16_t* Qb    = (uint16_t*)(ws);                    // 50331648
  uint16_t* Kb    = (uint16_t*)(ws + 50331648);         // 50331648
  uint16_t* WT    = (uint16_t*)(ws + 100663296);        // 2359296
  uint16_t* WqaT  = (uint16_t*)(ws + 103022592);        // 24576
  uint16_t* WkaT  = (uint16_t*)(ws + 103047168);        // 196608
  float*    accum = (float*)   (ws + 103243776);        // 49920
  float* sume   = accum;               // 96
  float* sume2  = accum + 96;          // 96
  float* sumeq  = accum + 192;         // 6144
  float* sume2k = accum + 192 + 6144;  // 6144
  float* qctx   = (float*)(ws + 103293696);             // 24576

  hipMemsetAsync(accum, 0, 12480 * sizeof(float), stream);

  prep_kernel<<<12624, 256, 0, stream>>>(x, Wq, Wk, Wqa, Xb, WT, WqaT);
  gemm_qk<<<3072, 256, 0, stream>>>(Xb, WT, Qb, Kb);
  scoresum_kernel<<<512, 256, 0, stream>>>(Qb, WqaT, mask, 0, sumeq, sume);
  ctxkaeff_kernel<<<384, 256, 0, stream>>>(sumeq, sume, Wka, WkaT, qctx);
  scoresum_kernel<<<512, 256, 0, stream>>>(Kb, WkaT, mask, 12288, sume2k, sume2);
  out_kernel<<<dim3(96, 32), 256, 0, stream>>>(Qb, qctx, sume2k, sume2, Wo, out);
}